// Round 9
// baseline (125.535 us; speedup 1.0000x reference)
//
#include <hip/hip_runtime.h>
#include <hip/hip_bf16.h>
#include <math.h>

// Two-pass QKV attention (gfx950).
// Pass 1 (prep): qkv fp32 -> bf16 scratch: Q^T [h][t][c] (*scale*log2e),
//                K^T [h][s][c] (*scale), V [h][c][s].  (R21 ILP-2, passing)
// Pass 2 (attn): K+V LDS tiles via global_load_lds DMA (XOR-swizzled),
//   2q x 2s wave split, BM=128. l-sum via ones-A MFMA. No-max softmax.
// History: R16/R17 passing @43.4us. Period (1.36us/barrier-interval) is
//   invariant to occupancy (8<->16 waves/CU), per-wave work (18<->36
//   MFMA/period), setprio, VALU diet => skeleton-bound (barrier + drain +
//   latency chains), not throughput-bound.
// R18/R19/R20/R22: FOUR paper-correct reschedules (deferred-PV x2,
//   in-iteration reorder, counted-vmcnt triple-buffer) all failed with
//   varying absmax. Rule adopted: only full-drain __syncthreads, only
//   in-iteration consumption, compute body order verbatim R17.
// R23 (this round): BK 64->128 — TWO K/V tiles per barrier period, the
//   complementary experiment to R16 (which doubled q-work per period for
//   free). Periods 32->16; per-period structure identical to R17: barrier
//   (full drain) -> stage next PAIR (8 cp16/wave) -> COMPUTE(tile A) ->
//   COMPUTE(tile B), body verbatim. Decisive: skeleton-bound => ~24-30us;
//   work-bound => flat. LDS 65KB (redbuf dropped; epilogue reuses dead
//   tile buffers as fp32 scratch), 2 blocks/CU.

#define T_LEN 2048
#define NH    32
#define D     64
#define QLD   2048
#define LSTR  72
#define BM    128
#define NQ    4

using f32x4 = __attribute__((ext_vector_type(4))) float;
using s16x8 = __attribute__((ext_vector_type(8))) short;
using s16x4 = __attribute__((ext_vector_type(4))) short;
using u32x4 = __attribute__((ext_vector_type(4))) unsigned;

__device__ __forceinline__ short f2bf(float f) {
    union { float f; unsigned u; } x; x.f = f;
    unsigned r = x.u + 0x7fffu + ((x.u >> 16) & 1u);   // RNE
    return (short)(r >> 16);
}

#if __has_builtin(__builtin_amdgcn_exp2f)
#define EXP2(x) __builtin_amdgcn_exp2f(x)
#else
#define EXP2(x) __expf(0.6931471805599453f * (x))
#endif

// lo16 = bf16(a), hi16 = bf16(b) — single instr, RNE (T12 recipe)
__device__ __forceinline__ unsigned pack2bf(float a, float b) {
    unsigned r;
    asm("v_cvt_pk_bf16_f32 %0, %1, %2" : "=v"(r) : "v"(a), "v"(b));
    return r;
}

// async 16B/lane global->LDS DMA; lds dst = l + lane*16 (wave-uniform l)
__device__ __forceinline__ void cp16(const short* g, short* l) {
    __builtin_amdgcn_global_load_lds(
        (const __attribute__((address_space(1))) void*)g,
        (__attribute__((address_space(3))) void*)l, 16, 0, 0);
}

// ---------------- pass 1: convert + transpose (ILP-2, R21) ----------------
__global__ __launch_bounds__(256, 4)
void prep(const float* __restrict__ qkv, short* __restrict__ ws16)
{
    __shared__ __align__(16) short tile[64 * LSTR];
    const int tid  = threadIdx.x;
    const int t0   = blockIdx.x * 128;    // two 64-t tiles per block
    const int head = blockIdx.y;
    const int kind = blockIdx.z;          // 0=Q, 1=K, 2=V
    const int b = head >> 3, h = head & 7;

    short* qt = ws16;                                   // [NH][T][D]
    short* kt = ws16 + (size_t)NH * T_LEN * D;          // [NH][T][D]
    short* vb = kt   + (size_t)NH * T_LEN * D;          // [NH][D][T]

    if (kind == 2) {
        const float* src = qkv + (size_t)(b * 1536 + 1024 + h * 64) * QLD;
        int c = tid >> 2, seg = (tid & 3) * 16;
        const float* p = src + (size_t)c * QLD + t0 + seg;
        short* dst = vb + ((size_t)head * D + c) * T_LEN + t0 + seg;
        f32x4 a0 = *(const f32x4*)(p);
        f32x4 a1 = *(const f32x4*)(p + 4);
        f32x4 a2 = *(const f32x4*)(p + 8);
        f32x4 a3 = *(const f32x4*)(p + 12);
        f32x4 b0 = *(const f32x4*)(p + 64);
        f32x4 b1 = *(const f32x4*)(p + 68);
        f32x4 b2 = *(const f32x4*)(p + 72);
        f32x4 b3 = *(const f32x4*)(p + 76);
        s16x8 w;
        w[0]=f2bf(a0[0]); w[1]=f2bf(a0[1]); w[2]=f2bf(a0[2]); w[3]=f2bf(a0[3]);
        w[4]=f2bf(a1[0]); w[5]=f2bf(a1[1]); w[6]=f2bf(a1[2]); w[7]=f2bf(a1[3]);
        *(s16x8*)(dst) = w;
        w[0]=f2bf(a2[0]); w[1]=f2bf(a2[1]); w[2]=f2bf(a2[2]); w[3]=f2bf(a2[3]);
        w[4]=f2bf(a3[0]); w[5]=f2bf(a3[1]); w[6]=f2bf(a3[2]); w[7]=f2bf(a3[3]);
        *(s16x8*)(dst + 8) = w;
        w[0]=f2bf(b0[0]); w[1]=f2bf(b0[1]); w[2]=f2bf(b0[2]); w[3]=f2bf(b0[3]);
        w[4]=f2bf(b1[0]); w[5]=f2bf(b1[1]); w[6]=f2bf(b1[2]); w[7]=f2bf(b1[3]);
        *(s16x8*)(dst + 64) = w;
        w[0]=f2bf(b2[0]); w[1]=f2bf(b2[1]); w[2]=f2bf(b2[2]); w[3]=f2bf(b2[3]);
        w[4]=f2bf(b3[0]); w[5]=f2bf(b3[1]); w[6]=f2bf(b3[2]); w[7]=f2bf(b3[3]);
        *(s16x8*)(dst + 72) = w;
        return;
    }

    const float sc = (kind == 0) ? 0.35355339059327373f * 1.4426950408889634f
                                 : 0.35355339059327373f;
    const float* src = qkv + (size_t)(b * 1536 + kind * 512 + h * 64) * QLD;
    short* dst = (kind == 0 ? qt : kt) + ((size_t)head * T_LEN + t0) * D;

    int m = tid & 15, c4 = (tid >> 4) << 2;
    const float* base = src + (size_t)c4 * QLD + t0 + 4 * m;
    const int row = tid >> 3;              // 0..31
    const int off = (tid & 7) * 8;         // shorts

    f32x4 a0 = *(const f32x4*)base;
    f32x4 a1 = *(const f32x4*)(base + QLD);
    f32x4 a2 = *(const f32x4*)(base + 2 * QLD);
    f32x4 a3 = *(const f32x4*)(base + 3 * QLD);
    f32x4 b0 = *(const f32x4*)(base + 64);
    f32x4 b1 = *(const f32x4*)(base + QLD + 64);
    f32x4 b2 = *(const f32x4*)(base + 2 * QLD + 64);
    f32x4 b3 = *(const f32x4*)(base + 3 * QLD + 64);

    {   // tile A: transpose via LDS
        #pragma unroll
        for (int j = 0; j < 4; ++j) {
            s16x4 w;
            w[0]=f2bf(a0[j]*sc); w[1]=f2bf(a1[j]*sc); w[2]=f2bf(a2[j]*sc); w[3]=f2bf(a3[j]*sc);
            *(s16x4*)&tile[(4 * m + j) * LSTR + c4] = w;
        }
    }
    __syncthreads();
    {
        *(s16x8*)(dst + (size_t)row * D + off)        = *(const s16x8*)&tile[row * LSTR + off];
        *(s16x8*)(dst + (size_t)(row + 32) * D + off) = *(const s16x8*)&tile[(row + 32) * LSTR + off];
    }
    __syncthreads();   // WAR: tile A fully read before tile B store
    {   // tile B
        #pragma unroll
        for (int j = 0; j < 4; ++j) {
            s16x4 w;
            w[0]=f2bf(b0[j]*sc); w[1]=f2bf(b1[j]*sc); w[2]=f2bf(b2[j]*sc); w[3]=f2bf(b3[j]*sc);
            *(s16x4*)&tile[(4 * m + j) * LSTR + c4] = w;
        }
    }
    __syncthreads();
    {
        short* dstB = dst + 64 * D;
        *(s16x8*)(dstB + (size_t)row * D + off)        = *(const s16x8*)&tile[row * LSTR + off];
        *(s16x8*)(dstB + (size_t)(row + 32) * D + off) = *(const s16x8*)&tile[(row + 32) * LSTR + off];
    }
}

// ---------------- pass 2: attention (R17 structure, BK=128 pair) ----------
__global__ __launch_bounds__(256, 2)
void attn(const short* __restrict__ ws16, float* __restrict__ out)
{
    // Ping-pong PAIR buffers. Each buffer holds 2 consecutive 64-s tiles.
    // Per-tile layout/swizzle identical to R17:
    // K: 64 s-rows x 64 shorts, chunk slot c holds global 16B-chunk
    //    c ^ sK(row), sK(r) = (r&3)|(((r>>3)&1)<<2).
    // V: 64 c-rows x 64 shorts, chunk slot c holds global chunk c ^ (r&7).
    __shared__ __align__(16) short ktile[2][2 * 64 * 64];   // [buf][tile 0/1]
    __shared__ __align__(16) short vtile[2][2 * 64 * 64];
    __shared__ float lbuf[4][64];

    const int tid  = threadIdx.x;
    const int w    = tid >> 6;
    const int qh   = w >> 1;               // q-half (64 rows)
    const int sq   = w & 1;                // s-half of each 64-s tile
    const int lane = tid & 63;
    const int l16  = lane & 15;
    const int quad = lane >> 4;

    // XCD swizzle (verified R6/R7): head ≡ bid (mod 8).
    const int bid  = blockIdx.x;
    const int head = (bid & 7) + 8 * ((bid >> 3) & 3);
    const int t0   = (bid >> 5) * BM;

    const short* qt = ws16 + (size_t)head * T_LEN * D;
    const short* kt = ws16 + (size_t)NH * T_LEN * D + (size_t)head * T_LEN * D;
    const short* vb = ws16 + 2 * (size_t)NH * T_LEN * D + (size_t)head * D * T_LEN;
    float*       op = out  + (size_t)head * 64 * QLD;

    short* kls = &ktile[0][0];
    short* vls = &vtile[0][0];

    // Q B-frags: this wave's 64 q-rows (t0 + qh*64 + nq*16 + l16)
    s16x8 bq[NQ][2];
    #pragma unroll
    for (int nq = 0; nq < NQ; ++nq) {
        const short* qrow = qt + (size_t)(t0 + qh * 64 + nq * 16 + l16) * D + quad * 8;
        bq[nq][0] = *(const s16x8*)qrow;
        bq[nq][1] = *(const s16x8*)(qrow + 32);
    }

    // ones A-tile for the l-sum MFMA (bf16 1.0 = 0x3F80)
    s16x8 ones;
    #pragma unroll
    for (int i = 0; i < 8; ++i) ones[i] = (short)0x3F80;

    const f32x4 z4 = f32x4{0.f, 0.f, 0.f, 0.f};

    f32x4 o[NQ][4];
    f32x4 lacc[NQ];
    #pragma unroll
    for (int nq = 0; nq < NQ; ++nq) {
        lacc[nq] = z4;
        #pragma unroll
        for (int ct = 0; ct < 4; ++ct) o[nq][ct] = z4;
    }

    // permuted K row: S C-rows (quad*4+r) land at s = g*32 + quad*8 + r + 4*sub
    const int kperm = (l16 >> 2) * 8 + (l16 & 3);
    const int ksw   = (l16 & 3) | (((l16 >> 2) & 1) << 2);   // = sK(kperm+4sub)
    const int srow  = lane >> 3;       // staging: row within 8-row group
    const int schk  = lane & 7;        // staging: chunk slot
    const int g     = sq;              // this wave's 32-s half

    // staging: wave w stages rows w*16..w*16+15 of each K and V tile.
    const int rl0 = w * 16 + srow;
    const int rl1 = rl0 + 8;
    const int sk0 = (srow & 3) | (((w * 2 + 0) & 1) << 2);
    const int sk1 = (srow & 3) | (((w * 2 + 1) & 1) << 2);
    const short* kge0 = kt + (size_t)rl0 * D + ((schk ^ sk0) << 3);
    const short* kge1 = kt + (size_t)rl1 * D + ((schk ^ sk1) << 3);
    const short* vge0 = vb + (size_t)rl0 * T_LEN + ((schk ^ srow) << 3);
    const short* vge1 = vb + (size_t)rl1 * T_LEN + ((schk ^ srow) << 3);

    // ---- prologue: DMA tile pair 0 (tiles 0,1) into buf 0 ----
    cp16(kge0,          kls + w * 1024);
    cp16(kge1,          kls + w * 1024 + 512);
    cp16(vge0,          vls + w * 1024);
    cp16(vge1,          vls + w * 1024 + 512);
    cp16(kge0 + 64 * D, kls + 4096 + w * 1024);
    cp16(kge1 + 64 * D, kls + 4096 + w * 1024 + 512);
    cp16(vge0 + 64,     vls + 4096 + w * 1024);
    cp16(vge1 + 64,     vls + 4096 + w * 1024 + 512);

    // running DMA pointers for the next pair (tiles 2,3)
    const short* kp0 = kge0 + 2 * 64 * D;
    const short* kp1 = kge1 + 2 * 64 * D;
    const short* vp0 = vge0 + 2 * 64;
    const short* vp1 = vge1 + 2 * 64;

// R17 compute body, verbatim, on per-tile bases KB/VB
#define COMPUTE(KB, VB) do { \
    u32x4 bp[NQ]; \
    _Pragma("unroll") \
    for (int sub = 0; sub < 2; ++sub) { \
        const int R  = g * 32 + kperm + 4 * sub; \
        const int c0 = (quad ^ ksw) << 3; \
        s16x8 ak0 = *(const s16x8*)&(KB)[R * 64 + c0]; \
        s16x8 ak1 = *(const s16x8*)&(KB)[R * 64 + (c0 ^ 32)]; \
        _Pragma("unroll") \
        for (int nq = 0; nq < NQ; ++nq) { \
            f32x4 acc; \
            acc = __builtin_amdgcn_mfma_f32_16x16x32_bf16(ak0, bq[nq][0], z4, 0, 0, 0); \
            acc = __builtin_amdgcn_mfma_f32_16x16x32_bf16(ak1, bq[nq][1], acc, 0, 0, 0); \
            bp[nq][sub * 2]     = pack2bf(EXP2(acc[0]), EXP2(acc[1])); \
            bp[nq][sub * 2 + 1] = pack2bf(EXP2(acc[2]), EXP2(acc[3])); \
        } \
    } \
    s16x8 p[NQ]; \
    _Pragma("unroll") \
    for (int nq = 0; nq < NQ; ++nq) p[nq] = __builtin_bit_cast(s16x8, bp[nq]); \
    __builtin_amdgcn_s_setprio(1); \
    _Pragma("unroll") \
    for (int nq = 0; nq < NQ; ++nq) \
        lacc[nq] = __builtin_amdgcn_mfma_f32_16x16x32_bf16(ones, p[nq], lacc[nq], 0, 0, 0); \
    _Pragma("unroll") \
    for (int ct = 0; ct < 4; ++ct) { \
        const int r = ct * 16 + l16; \
        s16x8 av = *(const s16x8*)&(VB)[r * 64 + ((((g * 4 + quad) ^ (l16 & 7))) << 3)]; \
        _Pragma("unroll") \
        for (int nq = 0; nq < NQ; ++nq) \
            o[nq][ct] = __builtin_amdgcn_mfma_f32_16x16x32_bf16(av, p[nq], o[nq][ct], 0, 0, 0); \
    } \
    __builtin_amdgcn_s_setprio(0); \
} while (0)

    // ---- main loop: 16 barrier periods, one tile PAIR each ----
    #pragma unroll 2
    for (int it = 0; it < T_LEN / 128; ++it) {
        const int cur = it & 1;
        const int cb  = cur * 8192;        // pair-buffer base (shorts)
        __syncthreads();   // full drain: buf[cur] resident; buf[cur^1] reads done

        // ---- stage next pair into buf[cur^1] (8 cp16/wave, async) ----
        if (it + 1 < T_LEN / 128) {
            const int nb = (cur ^ 1) * 8192;
            cp16(kp0, kls + nb + w * 1024);               kp0 += 64 * D;
            cp16(kp1, kls + nb + w * 1024 + 512);         kp1 += 64 * D;
            cp16(vp0, vls + nb + w * 1024);               vp0 += 64;
            cp16(vp1, vls + nb + w * 1024 + 512);         vp1 += 64;
            cp16(kp0, kls + nb + 4096 + w * 1024);        kp0 += 64 * D;
            cp16(kp1, kls + nb + 4096 + w * 1024 + 512);  kp1 += 64 * D;
            cp16(vp0, vls + nb + 4096 + w * 1024);        vp0 += 64;
            cp16(vp1, vls + nb + 4096 + w * 1024 + 512);  vp1 += 64;
        }

        // ---- compute both tiles of the pair (R17 body x2) ----
        COMPUTE(kls + cb,        vls + cb);
        COMPUTE(kls + cb + 4096, vls + cb + 4096);
    }
#undef COMPUTE

    // ---- epilogue: s-pair reduction (waves 2qh and 2qh+1) ----
    // lacc[nq][0] holds this wave's full s-half row sum for t=nq*16+l16.
    if (quad == 0) {
        #pragma unroll
        for (int nq = 0; nq < NQ; ++nq) lbuf[w][nq * 16 + l16] = lacc[nq][0];
    }
    __syncthreads();   // all tile reads done; lbuf visible; tiles reusable

    // per-qh fp32 scratch in the (now free) tile buffers: 64 x 68 fp32
    float* red = (float*)(qh == 0 ? (void*)kls : (void*)vls);
    if (sq == 1) {
        #pragma unroll
        for (int nq = 0; nq < NQ; ++nq)
            #pragma unroll
            for (int ct = 0; ct < 4; ++ct)
                *(f32x4*)&red[(nq * 16 + l16) * 68 + ct * 16 + quad * 4] = o[nq][ct];
    }
    __syncthreads();
    if (sq == 0) {
        #pragma unroll
        for (int nq = 0; nq < NQ; ++nq) {
            const int tr = nq * 16 + l16;
            const float inv = 1.f / (lbuf[qh * 2][tr] + lbuf[qh * 2 + 1][tr]);
            const int tq = t0 + qh * 64 + tr;
            #pragma unroll
            for (int ct = 0; ct < 4; ++ct) {
                f32x4 a = *(const f32x4*)&red[tr * 68 + ct * 16 + quad * 4];
                f32x4 v = o[nq][ct] + a;
                #pragma unroll
                for (int r = 0; r < 4; ++r) {
                    const int c = ct * 16 + quad * 4 + r;
                    op[(size_t)c * QLD + tq] = v[r] * inv;
                }
            }
        }
    }
}

extern "C" void kernel_launch(void* const* d_in, const int* in_sizes, int n_in,
                              void* d_out, int out_size, void* d_ws, size_t ws_size,
                              hipStream_t stream) {
    const float* qkv = (const float*)d_in[0];
    float* out = (float*)d_out;
    short* ws16 = (short*)d_ws;          // 3 * 32*2048*64 bf16 = 24 MB

    prep<<<dim3(T_LEN / 128, NH, 3), dim3(256), 0, stream>>>(qkv, ws16);
    attn<<<dim3(T_LEN / BM * NH), dim3(256), 0, stream>>>(ws16, out);
}

// Round 10
// 124.912 us; speedup vs baseline: 1.0050x; 1.0050x over previous
//
#include <hip/hip_runtime.h>
#include <hip/hip_bf16.h>
#include <math.h>

// Two-pass QKV attention (gfx950).
// Pass 1 (prep): qkv fp32 -> bf16 scratch: Q^T [h][t][c] (*scale*log2e),
//                K^T [h][s][c] (*scale), V [h][c][s].  (R21 ILP-2, passing)
// Pass 2 (attn): R17 structure verbatim (passing, 43.4us): K+V ping-pong
//   LDS tiles via global_load_lds DMA (XOR-swizzled), 2q x 2s wave split,
//   BM=128, full-drain __syncthreads per 64-s tile, l-sum via ones-A MFMA,
//   no-max softmax, P in regs via kperm trick.
// Findings: wall ~44us invariant to occupancy (R15/R16), work/wave (R16),
//   barrier-period count (R23 BK=128: flat). Sum-of-pipes model matches
//   wall exactly: MFMA 1397 + LDS ~1030 + trans ~512 + VALU ~420 ~= 3360
//   cyc/CU/tile vs measured 3256 => ZERO cross-pipe overlap. Cause: all
//   waves/blocks on a CU run the same phase sequence in-phase (simultaneous
//   launch, identical periods, barrier lockstep within block).
// R18/R19/R20/R22: four paper-correct reschedules failed with varying
//   absmax => schedule surgery barred; only zero-semantic changes allowed.
// R24 (this round): PHASE DECORRELATION. Block-dependent startup delay
//   (hash(bid) -> 0..~4000 cyc via s_sleep loop) staggers co-resident
//   blocks so one block's MFMA burst overlaps the other's exp/LDS burst.
//   Anti-phase is self-sustaining (solo phases run faster, preserving the
//   offset). Pure time-shift: no instruction/address/sync change.

#define T_LEN 2048
#define NH    32
#define D     64
#define QLD   2048
#define LSTR  72
#define BM    128
#define NQ    4

using f32x4 = __attribute__((ext_vector_type(4))) float;
using s16x8 = __attribute__((ext_vector_type(8))) short;
using s16x4 = __attribute__((ext_vector_type(4))) short;
using u32x4 = __attribute__((ext_vector_type(4))) unsigned;

__device__ __forceinline__ short f2bf(float f) {
    union { float f; unsigned u; } x; x.f = f;
    unsigned r = x.u + 0x7fffu + ((x.u >> 16) & 1u);   // RNE
    return (short)(r >> 16);
}

#if __has_builtin(__builtin_amdgcn_exp2f)
#define EXP2(x) __builtin_amdgcn_exp2f(x)
#else
#define EXP2(x) __expf(0.6931471805599453f * (x))
#endif

// lo16 = bf16(a), hi16 = bf16(b) — single instr, RNE (T12 recipe)
__device__ __forceinline__ unsigned pack2bf(float a, float b) {
    unsigned r;
    asm("v_cvt_pk_bf16_f32 %0, %1, %2" : "=v"(r) : "v"(a), "v"(b));
    return r;
}

// async 16B/lane global->LDS DMA; lds dst = l + lane*16 (wave-uniform l)
__device__ __forceinline__ void cp16(const short* g, short* l) {
    __builtin_amdgcn_global_load_lds(
        (const __attribute__((address_space(1))) void*)g,
        (__attribute__((address_space(3))) void*)l, 16, 0, 0);
}

// ---------------- pass 1: convert + transpose (ILP-2, R21) ----------------
__global__ __launch_bounds__(256, 4)
void prep(const float* __restrict__ qkv, short* __restrict__ ws16)
{
    __shared__ __align__(16) short tile[64 * LSTR];
    const int tid  = threadIdx.x;
    const int t0   = blockIdx.x * 128;    // two 64-t tiles per block
    const int head = blockIdx.y;
    const int kind = blockIdx.z;          // 0=Q, 1=K, 2=V
    const int b = head >> 3, h = head & 7;

    short* qt = ws16;                                   // [NH][T][D]
    short* kt = ws16 + (size_t)NH * T_LEN * D;          // [NH][T][D]
    short* vb = kt   + (size_t)NH * T_LEN * D;          // [NH][D][T]

    if (kind == 2) {
        const float* src = qkv + (size_t)(b * 1536 + 1024 + h * 64) * QLD;
        int c = tid >> 2, seg = (tid & 3) * 16;
        const float* p = src + (size_t)c * QLD + t0 + seg;
        short* dst = vb + ((size_t)head * D + c) * T_LEN + t0 + seg;
        f32x4 a0 = *(const f32x4*)(p);
        f32x4 a1 = *(const f32x4*)(p + 4);
        f32x4 a2 = *(const f32x4*)(p + 8);
        f32x4 a3 = *(const f32x4*)(p + 12);
        f32x4 b0 = *(const f32x4*)(p + 64);
        f32x4 b1 = *(const f32x4*)(p + 68);
        f32x4 b2 = *(const f32x4*)(p + 72);
        f32x4 b3 = *(const f32x4*)(p + 76);
        s16x8 w;
        w[0]=f2bf(a0[0]); w[1]=f2bf(a0[1]); w[2]=f2bf(a0[2]); w[3]=f2bf(a0[3]);
        w[4]=f2bf(a1[0]); w[5]=f2bf(a1[1]); w[6]=f2bf(a1[2]); w[7]=f2bf(a1[3]);
        *(s16x8*)(dst) = w;
        w[0]=f2bf(a2[0]); w[1]=f2bf(a2[1]); w[2]=f2bf(a2[2]); w[3]=f2bf(a2[3]);
        w[4]=f2bf(a3[0]); w[5]=f2bf(a3[1]); w[6]=f2bf(a3[2]); w[7]=f2bf(a3[3]);
        *(s16x8*)(dst + 8) = w;
        w[0]=f2bf(b0[0]); w[1]=f2bf(b0[1]); w[2]=f2bf(b0[2]); w[3]=f2bf(b0[3]);
        w[4]=f2bf(b1[0]); w[5]=f2bf(b1[1]); w[6]=f2bf(b1[2]); w[7]=f2bf(b1[3]);
        *(s16x8*)(dst + 64) = w;
        w[0]=f2bf(b2[0]); w[1]=f2bf(b2[1]); w[2]=f2bf(b2[2]); w[3]=f2bf(b2[3]);
        w[4]=f2bf(b3[0]); w[5]=f2bf(b3[1]); w[6]=f2bf(b3[2]); w[7]=f2bf(b3[3]);
        *(s16x8*)(dst + 72) = w;
        return;
    }

    const float sc = (kind == 0) ? 0.35355339059327373f * 1.4426950408889634f
                                 : 0.35355339059327373f;
    const float* src = qkv + (size_t)(b * 1536 + kind * 512 + h * 64) * QLD;
    short* dst = (kind == 0 ? qt : kt) + ((size_t)head * T_LEN + t0) * D;

    int m = tid & 15, c4 = (tid >> 4) << 2;
    const float* base = src + (size_t)c4 * QLD + t0 + 4 * m;
    const int row = tid >> 3;              // 0..31
    const int off = (tid & 7) * 8;         // shorts

    f32x4 a0 = *(const f32x4*)base;
    f32x4 a1 = *(const f32x4*)(base + QLD);
    f32x4 a2 = *(const f32x4*)(base + 2 * QLD);
    f32x4 a3 = *(const f32x4*)(base + 3 * QLD);
    f32x4 b0 = *(const f32x4*)(base + 64);
    f32x4 b1 = *(const f32x4*)(base + QLD + 64);
    f32x4 b2 = *(const f32x4*)(base + 2 * QLD + 64);
    f32x4 b3 = *(const f32x4*)(base + 3 * QLD + 64);

    {   // tile A: transpose via LDS
        #pragma unroll
        for (int j = 0; j < 4; ++j) {
            s16x4 w;
            w[0]=f2bf(a0[j]*sc); w[1]=f2bf(a1[j]*sc); w[2]=f2bf(a2[j]*sc); w[3]=f2bf(a3[j]*sc);
            *(s16x4*)&tile[(4 * m + j) * LSTR + c4] = w;
        }
    }
    __syncthreads();
    {
        *(s16x8*)(dst + (size_t)row * D + off)        = *(const s16x8*)&tile[row * LSTR + off];
        *(s16x8*)(dst + (size_t)(row + 32) * D + off) = *(const s16x8*)&tile[(row + 32) * LSTR + off];
    }
    __syncthreads();   // WAR: tile A fully read before tile B store
    {   // tile B
        #pragma unroll
        for (int j = 0; j < 4; ++j) {
            s16x4 w;
            w[0]=f2bf(b0[j]*sc); w[1]=f2bf(b1[j]*sc); w[2]=f2bf(b2[j]*sc); w[3]=f2bf(b3[j]*sc);
            *(s16x4*)&tile[(4 * m + j) * LSTR + c4] = w;
        }
    }
    __syncthreads();
    {
        short* dstB = dst + 64 * D;
        *(s16x8*)(dstB + (size_t)row * D + off)        = *(const s16x8*)&tile[row * LSTR + off];
        *(s16x8*)(dstB + (size_t)(row + 32) * D + off) = *(const s16x8*)&tile[(row + 32) * LSTR + off];
    }
}

// ---------------- pass 2: attention (R17 FROZEN + phase-stagger) ----------
__global__ __launch_bounds__(256, 2)
void attn(const short* __restrict__ ws16, float* __restrict__ out)
{
    // Ping-pong tiles. K: 64 s-rows x 64 shorts, chunk slot c holds global
    // 16B-chunk c ^ sK(row), sK(r) = (r&3)|(((r>>3)&1)<<2).
    // V: 64 c-rows x 64 shorts, chunk slot c holds global chunk c ^ (r&7).
    __shared__ __align__(16) short ktile[2][64 * 64];
    __shared__ __align__(16) short vtile[2][64 * 64];
    __shared__ float lbuf[4][64];
    __shared__ float redbuf[2][64][68];    // [qh][tr][c] fp32 merge staging

    const int tid  = threadIdx.x;
    const int w    = tid >> 6;
    const int qh   = w >> 1;               // q-half (64 rows)
    const int sq   = w & 1;                // s-half of each 64-s tile
    const int lane = tid & 63;
    const int l16  = lane & 15;
    const int quad = lane >> 4;

    // XCD swizzle (verified R6/R7): head ≡ bid (mod 8).
    const int bid  = blockIdx.x;
    const int head = (bid & 7) + 8 * ((bid >> 3) & 3);
    const int t0   = (bid >> 5) * BM;

    // R24: phase-decorrelation startup delay. hash(bid) -> 0..31 units of
    // ~128 cyc (s_sleep 2) = 0..~4000 cyc ~ 0..1.2 barrier periods. Pure
    // time-shift; wave-uniform; zero semantic change.
    {
        const unsigned dly = (((unsigned)bid * 2654435761u) >> 27) & 31u;
        for (unsigned i = 0; i < dly; ++i) __builtin_amdgcn_s_sleep(2);
    }

    const short* qt = ws16 + (size_t)head * T_LEN * D;
    const short* kt = ws16 + (size_t)NH * T_LEN * D + (size_t)head * T_LEN * D;
    const short* vb = ws16 + 2 * (size_t)NH * T_LEN * D + (size_t)head * D * T_LEN;
    float*       op = out  + (size_t)head * 64 * QLD;

    // Q B-frags: this wave's 64 q-rows (t0 + qh*64 + nq*16 + l16)
    s16x8 bq[NQ][2];
    #pragma unroll
    for (int nq = 0; nq < NQ; ++nq) {
        const short* qrow = qt + (size_t)(t0 + qh * 64 + nq * 16 + l16) * D + quad * 8;
        bq[nq][0] = *(const s16x8*)qrow;
        bq[nq][1] = *(const s16x8*)(qrow + 32);
    }

    // ones A-tile for the l-sum MFMA (bf16 1.0 = 0x3F80)
    s16x8 ones;
    #pragma unroll
    for (int i = 0; i < 8; ++i) ones[i] = (short)0x3F80;

    // persistent zero seed for the QK accumulators
    const f32x4 z4 = f32x4{0.f, 0.f, 0.f, 0.f};

    f32x4 o[NQ][4];
    f32x4 lacc[NQ];
    #pragma unroll
    for (int nq = 0; nq < NQ; ++nq) {
        lacc[nq] = z4;
        #pragma unroll
        for (int ct = 0; ct < 4; ++ct) o[nq][ct] = z4;
    }

    // permuted K row: S C-rows (quad*4+r) land at s = g*32 + quad*8 + r + 4*sub
    const int kperm = (l16 >> 2) * 8 + (l16 & 3);
    const int ksw   = (l16 & 3) | (((l16 >> 2) & 1) << 2);   // = sK(kperm+4sub)
    const int srow  = lane >> 3;       // staging: row within 8-row group
    const int schk  = lane & 7;        // staging: chunk slot
    const int g     = sq;              // this wave's 32-s half

    // staging: wave w stages rows w*16..w*16+15 of K and V tiles.
    const int rl0 = w * 16 + srow;
    const int rl1 = rl0 + 8;
    const int sk0 = (srow & 3) | (((w * 2 + 0) & 1) << 2);
    const int sk1 = (srow & 3) | (((w * 2 + 1) & 1) << 2);
    const short* kge0 = kt + (size_t)rl0 * D + ((schk ^ sk0) << 3);
    const short* kge1 = kt + (size_t)rl1 * D + ((schk ^ sk1) << 3);
    const short* vge0 = vb + (size_t)rl0 * T_LEN + ((schk ^ srow) << 3);
    const short* vge1 = vb + (size_t)rl1 * T_LEN + ((schk ^ srow) << 3);

    // ---- prologue: DMA tile 0 into buf 0 ----
    cp16(kge0, &ktile[0][w * 1024]);
    cp16(kge1, &ktile[0][w * 1024 + 512]);
    cp16(vge0, &vtile[0][w * 1024]);
    cp16(vge1, &vtile[0][w * 1024 + 512]);

    // running DMA pointers for tile it+1 (strength-reduced)
    const short* kp0 = kge0 + 64 * D;
    const short* kp1 = kge1 + 64 * D;
    const short* vp0 = vge0 + 64;
    const short* vp1 = vge1 + 64;

    #pragma unroll 2
    for (int it = 0; it < T_LEN / 64; ++it) {
        const int cur = it & 1;
        __syncthreads();   // buf[cur] DMA drained; prior reads of buf[cur^1] done

        // ---- issue DMA for tile it+1 into buf[cur^1] (async all iter) ----
        if (it + 1 < T_LEN / 64) {
            cp16(kp0, &ktile[cur ^ 1][w * 1024]);        kp0 += 64 * D;
            cp16(kp1, &ktile[cur ^ 1][w * 1024 + 512]);  kp1 += 64 * D;
            cp16(vp0, &vtile[cur ^ 1][w * 1024]);        vp0 += 64;
            cp16(vp1, &vtile[cur ^ 1][w * 1024 + 512]);  vp1 += 64;
        }

        // ---- S' = K*Q on this wave's s-half; p = 2^s; pack ----
        u32x4 bp[NQ];
        #pragma unroll
        for (int sub = 0; sub < 2; ++sub) {
            const int R  = g * 32 + kperm + 4 * sub;
            const int c0 = (quad ^ ksw) << 3;
            s16x8 ak0 = *(const s16x8*)&ktile[cur][R * 64 + c0];
            s16x8 ak1 = *(const s16x8*)&ktile[cur][R * 64 + (c0 ^ 32)];
            #pragma unroll
            for (int nq = 0; nq < NQ; ++nq) {
                f32x4 acc;
                acc = __builtin_amdgcn_mfma_f32_16x16x32_bf16(ak0, bq[nq][0], z4, 0, 0, 0);
                acc = __builtin_amdgcn_mfma_f32_16x16x32_bf16(ak1, bq[nq][1], acc, 0, 0, 0);
                bp[nq][sub * 2]     = pack2bf(EXP2(acc[0]), EXP2(acc[1]));
                bp[nq][sub * 2 + 1] = pack2bf(EXP2(acc[2]), EXP2(acc[3]));
            }
        }
        // ---- O^T += V * P^T ; l += 1 * P^T (ones-MFMA row sum) ----
        s16x8 p[NQ];
        #pragma unroll
        for (int nq = 0; nq < NQ; ++nq) p[nq] = __builtin_bit_cast(s16x8, bp[nq]);
        __builtin_amdgcn_s_setprio(1);
        #pragma unroll
        for (int nq = 0; nq < NQ; ++nq)
            lacc[nq] = __builtin_amdgcn_mfma_f32_16x16x32_bf16(ones, p[nq], lacc[nq], 0, 0, 0);
        #pragma unroll
        for (int ct = 0; ct < 4; ++ct) {
            const int r = ct * 16 + l16;
            s16x8 av = *(const s16x8*)&vtile[cur][r * 64 + ((((g * 4 + quad) ^ (l16 & 7))) << 3)];
            #pragma unroll
            for (int nq = 0; nq < NQ; ++nq)
                o[nq][ct] = __builtin_amdgcn_mfma_f32_16x16x32_bf16(av, p[nq], o[nq][ct], 0, 0, 0);
        }
        __builtin_amdgcn_s_setprio(0);
    }

    // ---- epilogue: s-pair reduction (waves 2qh and 2qh+1) ----
    // lacc[nq][0] holds this wave's full s-half row sum for t=nq*16+l16 (all
    // C rows of the ones-MFMA are identical).
    if (quad == 0) {
        #pragma unroll
        for (int nq = 0; nq < NQ; ++nq) lbuf[w][nq * 16 + l16] = lacc[nq][0];
    }
    __syncthreads();   // all tile reads done; lbuf visible

    if (sq == 1) {
        #pragma unroll
        for (int nq = 0; nq < NQ; ++nq)
            #pragma unroll
            for (int ct = 0; ct < 4; ++ct)
                *(f32x4*)&redbuf[qh][nq * 16 + l16][ct * 16 + quad * 4] = o[nq][ct];
    }
    __syncthreads();
    if (sq == 0) {
        #pragma unroll
        for (int nq = 0; nq < NQ; ++nq) {
            const int tr = nq * 16 + l16;
            const float inv = 1.f / (lbuf[qh * 2][tr] + lbuf[qh * 2 + 1][tr]);
            const int tq = t0 + qh * 64 + tr;
            #pragma unroll
            for (int ct = 0; ct < 4; ++ct) {
                f32x4 a = *(const f32x4*)&redbuf[qh][tr][ct * 16 + quad * 4];
                f32x4 v = o[nq][ct] + a;
                #pragma unroll
                for (int r = 0; r < 4; ++r) {
                    const int c = ct * 16 + quad * 4 + r;
                    op[(size_t)c * QLD + tq] = v[r] * inv;
                }
            }
        }
    }
}

extern "C" void kernel_launch(void* const* d_in, const int* in_sizes, int n_in,
                              void* d_out, int out_size, void* d_ws, size_t ws_size,
                              hipStream_t stream) {
    const float* qkv = (const float*)d_in[0];
    float* out = (float*)d_out;
    short* ws16 = (short*)d_ws;          // 3 * 32*2048*64 bf16 = 24 MB

    prep<<<dim3(T_LEN / 128, NH, 3), dim3(256), 0, stream>>>(qkv, ws16);
    attn<<<dim3(T_LEN / BM * NH), dim3(256), 0, stream>>>(ws16, out);
}

// Round 11
// 123.993 us; speedup vs baseline: 1.0124x; 1.0074x over previous
//
#include <hip/hip_runtime.h>
#include <hip/hip_bf16.h>
#include <math.h>

// Two-pass QKV attention (gfx950).
// Pass 1 (prep): qkv fp32 -> bf16 scratch: Q^T [h][t][c] (*scale*log2e),
//                K^T [h][s][c] (*scale), V [h][c][s].
// Pass 2 (attn): R17 structure FROZEN (passing, 43.4us): K+V ping-pong LDS
//   tiles via global_load_lds DMA (XOR-swizzled), 2q x 2s wave split,
//   BM=128, full-drain __syncthreads per 64-s tile, l-sum via ones-A MFMA,
//   no-max softmax, P in regs via kperm trick.
// attn findings: wall ~43.4us invariant to occupancy (R15/R16), work/wave
//   (R16), barrier-period count (R23), phase stagger (R24). Only instruction
//   -count cuts ever helped (R15). Four reschedules (R18/R19/R20/R22) failed
//   correctness with varying absmax => schedule surgery barred. FROZEN.
// R25 (this round): prep optimization (prep is NOT cursed — R21 modified it
//   and passed; never profiled, < 43us, HBM roofline ~11us => the largest
//   identifiable slack). (1) V path fully coalesced: wave = 4 rows x 16
//   lanes x 16B = 256B contiguous per row per instruction (was 4-lane 64B
//   granules scattered over 16 rows, ~4x transactions); loads hoisted.
//   (2) all fp32->bf16 via v_cvt_pk_bf16_f32 (1 instr / 2 elems; RNE-
//   identical to the old f2bf chain, ~3x convert VALU cut).

#define T_LEN 2048
#define NH    32
#define D     64
#define QLD   2048
#define LSTR  72
#define BM    128
#define NQ    4

using f32x4 = __attribute__((ext_vector_type(4))) float;
using s16x8 = __attribute__((ext_vector_type(8))) short;
using s16x4 = __attribute__((ext_vector_type(4))) short;
using u32x4 = __attribute__((ext_vector_type(4))) unsigned;
using u32x2 = __attribute__((ext_vector_type(2))) unsigned;

#if __has_builtin(__builtin_amdgcn_exp2f)
#define EXP2(x) __builtin_amdgcn_exp2f(x)
#else
#define EXP2(x) __expf(0.6931471805599453f * (x))
#endif

// lo16 = bf16(a), hi16 = bf16(b) — single instr, RNE (T12 recipe)
__device__ __forceinline__ unsigned pack2bf(float a, float b) {
    unsigned r;
    asm("v_cvt_pk_bf16_f32 %0, %1, %2" : "=v"(r) : "v"(a), "v"(b));
    return r;
}

// async 16B/lane global->LDS DMA; lds dst = l + lane*16 (wave-uniform l)
__device__ __forceinline__ void cp16(const short* g, short* l) {
    __builtin_amdgcn_global_load_lds(
        (const __attribute__((address_space(1))) void*)g,
        (__attribute__((address_space(3))) void*)l, 16, 0, 0);
}

// ---------------- pass 1: convert + transpose (R25 coalesced+cvt_pk) ------
__global__ __launch_bounds__(256, 4)
void prep(const float* __restrict__ qkv, short* __restrict__ ws16)
{
    __shared__ __align__(16) short tile[64 * LSTR];
    const int tid  = threadIdx.x;
    const int t0   = blockIdx.x * 128;    // two 64-t tiles per block
    const int head = blockIdx.y;
    const int kind = blockIdx.z;          // 0=Q, 1=K, 2=V
    const int b = head >> 3, h = head & 7;

    short* qt = ws16;                                   // [NH][T][D]
    short* kt = ws16 + (size_t)NH * T_LEN * D;          // [NH][T][D]
    short* vb = kt   + (size_t)NH * T_LEN * D;          // [NH][D][T]

    if (kind == 2) {
        // V: [c][t] fp32 -> [c][t] bf16. Wave reads 4 rows x (16 lanes x
        // 16B = 256B contiguous) per instruction; stores 128B/row.
        const float* src = qkv + (size_t)(b * 1536 + 1024 + h * 64) * QLD + t0;
        short*       dst = vb  + (size_t)head * D * T_LEN + t0;
        const int r0  = tid >> 4;          // 0..15: row within step-group
        const int c16 = (tid & 15) * 4;    // float col within 64-col half

        f32x4 va[4][2];                    // all 8 loads in flight
        #pragma unroll
        for (int s = 0; s < 4; ++s) {
            const float* sr = src + (size_t)(s * 16 + r0) * QLD + c16;
            va[s][0] = *(const f32x4*)sr;
            va[s][1] = *(const f32x4*)(sr + 64);
        }
        #pragma unroll
        for (int s = 0; s < 4; ++s) {
            short* dr = dst + (size_t)(s * 16 + r0) * T_LEN + c16;
            u32x2 w0, w1;
            w0[0] = pack2bf(va[s][0][0], va[s][0][1]);
            w0[1] = pack2bf(va[s][0][2], va[s][0][3]);
            w1[0] = pack2bf(va[s][1][0], va[s][1][1]);
            w1[1] = pack2bf(va[s][1][2], va[s][1][3]);
            *(u32x2*)dr        = w0;
            *(u32x2*)(dr + 64) = w1;
        }
        return;
    }

    const float sc = (kind == 0) ? 0.35355339059327373f * 1.4426950408889634f
                                 : 0.35355339059327373f;
    const float* src = qkv + (size_t)(b * 1536 + kind * 512 + h * 64) * QLD;
    short* dst = (kind == 0 ? qt : kt) + ((size_t)head * T_LEN + t0) * D;

    int m = tid & 15, c4 = (tid >> 4) << 2;
    const float* base = src + (size_t)c4 * QLD + t0 + 4 * m;
    const int row = tid >> 3;              // 0..31
    const int off = (tid & 7) * 8;         // shorts

    // all 8 row-loads (tiles A and B) issued before any convert
    f32x4 a0 = *(const f32x4*)base;
    f32x4 a1 = *(const f32x4*)(base + QLD);
    f32x4 a2 = *(const f32x4*)(base + 2 * QLD);
    f32x4 a3 = *(const f32x4*)(base + 3 * QLD);
    f32x4 b0 = *(const f32x4*)(base + 64);
    f32x4 b1 = *(const f32x4*)(base + QLD + 64);
    f32x4 b2 = *(const f32x4*)(base + 2 * QLD + 64);
    f32x4 b3 = *(const f32x4*)(base + 3 * QLD + 64);

    {   // tile A: transpose via LDS (cvt_pk pairs along c)
        #pragma unroll
        for (int j = 0; j < 4; ++j) {
            u32x2 w;
            w[0] = pack2bf(a0[j] * sc, a1[j] * sc);
            w[1] = pack2bf(a2[j] * sc, a3[j] * sc);
            *(u32x2*)&tile[(4 * m + j) * LSTR + c4] = w;
        }
    }
    __syncthreads();
    {   // lane-contiguous coalesced rows [t][c] to global (16B/lane)
        *(s16x8*)(dst + (size_t)row * D + off)        = *(const s16x8*)&tile[row * LSTR + off];
        *(s16x8*)(dst + (size_t)(row + 32) * D + off) = *(const s16x8*)&tile[(row + 32) * LSTR + off];
    }
    __syncthreads();   // WAR: tile A fully read before tile B store
    {   // tile B
        #pragma unroll
        for (int j = 0; j < 4; ++j) {
            u32x2 w;
            w[0] = pack2bf(b0[j] * sc, b1[j] * sc);
            w[1] = pack2bf(b2[j] * sc, b3[j] * sc);
            *(u32x2*)&tile[(4 * m + j) * LSTR + c4] = w;
        }
    }
    __syncthreads();
    {
        short* dstB = dst + 64 * D;
        *(s16x8*)(dstB + (size_t)row * D + off)        = *(const s16x8*)&tile[row * LSTR + off];
        *(s16x8*)(dstB + (size_t)(row + 32) * D + off) = *(const s16x8*)&tile[(row + 32) * LSTR + off];
    }
}

// ---------------- pass 2: attention (R17 source, FROZEN) ----------------
__global__ __launch_bounds__(256, 2)
void attn(const short* __restrict__ ws16, float* __restrict__ out)
{
    // Ping-pong tiles. K: 64 s-rows x 64 shorts, chunk slot c holds global
    // 16B-chunk c ^ sK(row), sK(r) = (r&3)|(((r>>3)&1)<<2).
    // V: 64 c-rows x 64 shorts, chunk slot c holds global chunk c ^ (r&7).
    __shared__ __align__(16) short ktile[2][64 * 64];
    __shared__ __align__(16) short vtile[2][64 * 64];
    __shared__ float lbuf[4][64];
    __shared__ float redbuf[2][64][68];    // [qh][tr][c] fp32 merge staging

    const int tid  = threadIdx.x;
    const int w    = tid >> 6;
    const int qh   = w >> 1;               // q-half (64 rows)
    const int sq   = w & 1;                // s-half of each 64-s tile
    const int lane = tid & 63;
    const int l16  = lane & 15;
    const int quad = lane >> 4;

    // XCD swizzle (verified R6/R7): head ≡ bid (mod 8).
    const int bid  = blockIdx.x;
    const int head = (bid & 7) + 8 * ((bid >> 3) & 3);
    const int t0   = (bid >> 5) * BM;

    const short* qt = ws16 + (size_t)head * T_LEN * D;
    const short* kt = ws16 + (size_t)NH * T_LEN * D + (size_t)head * T_LEN * D;
    const short* vb = ws16 + 2 * (size_t)NH * T_LEN * D + (size_t)head * D * T_LEN;
    float*       op = out  + (size_t)head * 64 * QLD;

    // Q B-frags: this wave's 64 q-rows (t0 + qh*64 + nq*16 + l16)
    s16x8 bq[NQ][2];
    #pragma unroll
    for (int nq = 0; nq < NQ; ++nq) {
        const short* qrow = qt + (size_t)(t0 + qh * 64 + nq * 16 + l16) * D + quad * 8;
        bq[nq][0] = *(const s16x8*)qrow;
        bq[nq][1] = *(const s16x8*)(qrow + 32);
    }

    // ones A-tile for the l-sum MFMA (bf16 1.0 = 0x3F80)
    s16x8 ones;
    #pragma unroll
    for (int i = 0; i < 8; ++i) ones[i] = (short)0x3F80;

    // persistent zero seed for the QK accumulators
    const f32x4 z4 = f32x4{0.f, 0.f, 0.f, 0.f};

    f32x4 o[NQ][4];
    f32x4 lacc[NQ];
    #pragma unroll
    for (int nq = 0; nq < NQ; ++nq) {
        lacc[nq] = z4;
        #pragma unroll
        for (int ct = 0; ct < 4; ++ct) o[nq][ct] = z4;
    }

    // permuted K row: S C-rows (quad*4+r) land at s = g*32 + quad*8 + r + 4*sub
    const int kperm = (l16 >> 2) * 8 + (l16 & 3);
    const int ksw   = (l16 & 3) | (((l16 >> 2) & 1) << 2);   // = sK(kperm+4sub)
    const int srow  = lane >> 3;       // staging: row within 8-row group
    const int schk  = lane & 7;        // staging: chunk slot
    const int g     = sq;              // this wave's 32-s half

    // staging: wave w stages rows w*16..w*16+15 of K and V tiles.
    const int rl0 = w * 16 + srow;
    const int rl1 = rl0 + 8;
    const int sk0 = (srow & 3) | (((w * 2 + 0) & 1) << 2);
    const int sk1 = (srow & 3) | (((w * 2 + 1) & 1) << 2);
    const short* kge0 = kt + (size_t)rl0 * D + ((schk ^ sk0) << 3);
    const short* kge1 = kt + (size_t)rl1 * D + ((schk ^ sk1) << 3);
    const short* vge0 = vb + (size_t)rl0 * T_LEN + ((schk ^ srow) << 3);
    const short* vge1 = vb + (size_t)rl1 * T_LEN + ((schk ^ srow) << 3);

    // ---- prologue: DMA tile 0 into buf 0 ----
    cp16(kge0, &ktile[0][w * 1024]);
    cp16(kge1, &ktile[0][w * 1024 + 512]);
    cp16(vge0, &vtile[0][w * 1024]);
    cp16(vge1, &vtile[0][w * 1024 + 512]);

    // running DMA pointers for tile it+1 (strength-reduced)
    const short* kp0 = kge0 + 64 * D;
    const short* kp1 = kge1 + 64 * D;
    const short* vp0 = vge0 + 64;
    const short* vp1 = vge1 + 64;

    #pragma unroll 2
    for (int it = 0; it < T_LEN / 64; ++it) {
        const int cur = it & 1;
        __syncthreads();   // buf[cur] DMA drained; prior reads of buf[cur^1] done

        // ---- issue DMA for tile it+1 into buf[cur^1] (async all iter) ----
        if (it + 1 < T_LEN / 64) {
            cp16(kp0, &ktile[cur ^ 1][w * 1024]);        kp0 += 64 * D;
            cp16(kp1, &ktile[cur ^ 1][w * 1024 + 512]);  kp1 += 64 * D;
            cp16(vp0, &vtile[cur ^ 1][w * 1024]);        vp0 += 64;
            cp16(vp1, &vtile[cur ^ 1][w * 1024 + 512]);  vp1 += 64;
        }

        // ---- S' = K*Q on this wave's s-half; p = 2^s; pack ----
        u32x4 bp[NQ];
        #pragma unroll
        for (int sub = 0; sub < 2; ++sub) {
            const int R  = g * 32 + kperm + 4 * sub;
            const int c0 = (quad ^ ksw) << 3;
            s16x8 ak0 = *(const s16x8*)&ktile[cur][R * 64 + c0];
            s16x8 ak1 = *(const s16x8*)&ktile[cur][R * 64 + (c0 ^ 32)];
            #pragma unroll
            for (int nq = 0; nq < NQ; ++nq) {
                f32x4 acc;
                acc = __builtin_amdgcn_mfma_f32_16x16x32_bf16(ak0, bq[nq][0], z4, 0, 0, 0);
                acc = __builtin_amdgcn_mfma_f32_16x16x32_bf16(ak1, bq[nq][1], acc, 0, 0, 0);
                bp[nq][sub * 2]     = pack2bf(EXP2(acc[0]), EXP2(acc[1]));
                bp[nq][sub * 2 + 1] = pack2bf(EXP2(acc[2]), EXP2(acc[3]));
            }
        }
        // ---- O^T += V * P^T ; l += 1 * P^T (ones-MFMA row sum) ----
        s16x8 p[NQ];
        #pragma unroll
        for (int nq = 0; nq < NQ; ++nq) p[nq] = __builtin_bit_cast(s16x8, bp[nq]);
        __builtin_amdgcn_s_setprio(1);
        #pragma unroll
        for (int nq = 0; nq < NQ; ++nq)
            lacc[nq] = __builtin_amdgcn_mfma_f32_16x16x32_bf16(ones, p[nq], lacc[nq], 0, 0, 0);
        #pragma unroll
        for (int ct = 0; ct < 4; ++ct) {
            const int r = ct * 16 + l16;
            s16x8 av = *(const s16x8*)&vtile[cur][r * 64 + ((((g * 4 + quad) ^ (l16 & 7))) << 3)];
            #pragma unroll
            for (int nq = 0; nq < NQ; ++nq)
                o[nq][ct] = __builtin_amdgcn_mfma_f32_16x16x32_bf16(av, p[nq], o[nq][ct], 0, 0, 0);
        }
        __builtin_amdgcn_s_setprio(0);
    }

    // ---- epilogue: s-pair reduction (waves 2qh and 2qh+1) ----
    // lacc[nq][0] holds this wave's full s-half row sum for t=nq*16+l16 (all
    // C rows of the ones-MFMA are identical).
    if (quad == 0) {
        #pragma unroll
        for (int nq = 0; nq < NQ; ++nq) lbuf[w][nq * 16 + l16] = lacc[nq][0];
    }
    __syncthreads();   // all tile reads done; lbuf visible

    if (sq == 1) {
        #pragma unroll
        for (int nq = 0; nq < NQ; ++nq)
            #pragma unroll
            for (int ct = 0; ct < 4; ++ct)
                *(f32x4*)&redbuf[qh][nq * 16 + l16][ct * 16 + quad * 4] = o[nq][ct];
    }
    __syncthreads();
    if (sq == 0) {
        #pragma unroll
        for (int nq = 0; nq < NQ; ++nq) {
            const int tr = nq * 16 + l16;
            const float inv = 1.f / (lbuf[qh * 2][tr] + lbuf[qh * 2 + 1][tr]);
            const int tq = t0 + qh * 64 + tr;
            #pragma unroll
            for (int ct = 0; ct < 4; ++ct) {
                f32x4 a = *(const f32x4*)&redbuf[qh][tr][ct * 16 + quad * 4];
                f32x4 v = o[nq][ct] + a;
                #pragma unroll
                for (int r = 0; r < 4; ++r) {
                    const int c = ct * 16 + quad * 4 + r;
                    op[(size_t)c * QLD + tq] = v[r] * inv;
                }
            }
        }
    }
}

extern "C" void kernel_launch(void* const* d_in, const int* in_sizes, int n_in,
                              void* d_out, int out_size, void* d_ws, size_t ws_size,
                              hipStream_t stream) {
    const float* qkv = (const float*)d_in[0];
    float* out = (float*)d_out;
    short* ws16 = (short*)d_ws;          // 3 * 32*2048*64 bf16 = 24 MB

    prep<<<dim3(T_LEN / 128, NH, 3), dim3(256), 0, stream>>>(qkv, ws16);
    attn<<<dim3(T_LEN / BM * NH), dim3(256), 0, stream>>>(ws16, out);
}

// Round 12
// 121.420 us; speedup vs baseline: 1.0339x; 1.0212x over previous
//
#include <hip/hip_runtime.h>
#include <hip/hip_bf16.h>
#include <math.h>

// Two-pass QKV attention (gfx950).
// Pass 1 (prep): qkv fp32 -> bf16 scratch: K^T [h][s][c] (*scale), V [h][c][s].
//   (Q leg DELETED in R26 — attn gathers Q directly from fp32 qkv.)
// Pass 2 (attn): R17 loop/epilogue FROZEN (passing, 43.4us): K+V ping-pong
//   LDS tiles via global_load_lds DMA (XOR-swizzled), 2q x 2s wave split,
//   BM=128, full-drain __syncthreads per 64-s tile, l-sum via ones-A MFMA,
//   no-max softmax, P in regs via kperm trick.
// attn findings: wall ~43.4us invariant to occupancy (R15/R16), work/wave
//   (R16), barrier-period count (R23), phase stagger (R24). Only instruction
//   -count cuts ever helped (R15). Four reschedules (R18/R19/R20/R22) failed
//   correctness with varying absmax => loop schedule surgery barred. FROZEN.
// R25: prep V-path coalesced + cvt_pk everywhere (124.0us). Profile showed
//   the 256MB ws poison-fill (43us) is ONE-TIME, not per-iter; per-iter =
//   prep + attn + small resets.
// R26 (this round): delete prep's Q leg (1/3 of prep traffic + blocks).
//   Q is consumed once per attn block in the PROLOGUE (outside the cursed
//   loop) as register fragments -> per-lane gather direct from fp32 qkv
//   (stride-QLD, 64 dwords/thread, once per block), scale+cvt_pk in regs.
//   RNE-identical to the scratch path => bitwise-same Q fragments. attn
//   loop/epilogue byte-identical; prep grid z: 3->2.

#define T_LEN 2048
#define NH    32
#define D     64
#define QLD   2048
#define LSTR  72
#define BM    128
#define NQ    4

using f32x4 = __attribute__((ext_vector_type(4))) float;
using s16x8 = __attribute__((ext_vector_type(8))) short;
using s16x4 = __attribute__((ext_vector_type(4))) short;
using u32x4 = __attribute__((ext_vector_type(4))) unsigned;
using u32x2 = __attribute__((ext_vector_type(2))) unsigned;

#if __has_builtin(__builtin_amdgcn_exp2f)
#define EXP2(x) __builtin_amdgcn_exp2f(x)
#else
#define EXP2(x) __expf(0.6931471805599453f * (x))
#endif

// lo16 = bf16(a), hi16 = bf16(b) — single instr, RNE (T12 recipe)
__device__ __forceinline__ unsigned pack2bf(float a, float b) {
    unsigned r;
    asm("v_cvt_pk_bf16_f32 %0, %1, %2" : "=v"(r) : "v"(a), "v"(b));
    return r;
}

// async 16B/lane global->LDS DMA; lds dst = l + lane*16 (wave-uniform l)
__device__ __forceinline__ void cp16(const short* g, short* l) {
    __builtin_amdgcn_global_load_lds(
        (const __attribute__((address_space(1))) void*)g,
        (__attribute__((address_space(3))) void*)l, 16, 0, 0);
}

// ---------------- pass 1: convert + transpose (K, V only — R26) -----------
__global__ __launch_bounds__(256, 4)
void prep(const float* __restrict__ qkv, short* __restrict__ ws16)
{
    __shared__ __align__(16) short tile[64 * LSTR];
    const int tid  = threadIdx.x;
    const int t0   = blockIdx.x * 128;    // two 64-t tiles per block
    const int head = blockIdx.y;
    const int kind = blockIdx.z;          // 0=K, 1=V
    const int b = head >> 3, h = head & 7;

    short* kt = ws16 + (size_t)NH * T_LEN * D;          // [NH][T][D]
    short* vb = kt   + (size_t)NH * T_LEN * D;          // [NH][D][T]

    if (kind == 1) {
        // V: [c][t] fp32 -> [c][t] bf16. Wave reads 4 rows x (16 lanes x
        // 16B = 256B contiguous) per instruction; stores 128B/row.
        const float* src = qkv + (size_t)(b * 1536 + 1024 + h * 64) * QLD + t0;
        short*       dst = vb  + (size_t)head * D * T_LEN + t0;
        const int r0  = tid >> 4;          // 0..15: row within step-group
        const int c16 = (tid & 15) * 4;    // float col within 64-col half

        f32x4 va[4][2];                    // all 8 loads in flight
        #pragma unroll
        for (int s = 0; s < 4; ++s) {
            const float* sr = src + (size_t)(s * 16 + r0) * QLD + c16;
            va[s][0] = *(const f32x4*)sr;
            va[s][1] = *(const f32x4*)(sr + 64);
        }
        #pragma unroll
        for (int s = 0; s < 4; ++s) {
            short* dr = dst + (size_t)(s * 16 + r0) * T_LEN + c16;
            u32x2 w0, w1;
            w0[0] = pack2bf(va[s][0][0], va[s][0][1]);
            w0[1] = pack2bf(va[s][0][2], va[s][0][3]);
            w1[0] = pack2bf(va[s][1][0], va[s][1][1]);
            w1[1] = pack2bf(va[s][1][2], va[s][1][3]);
            *(u32x2*)dr        = w0;
            *(u32x2*)(dr + 64) = w1;
        }
        return;
    }

    // K: [c][s] fp32 -> [s][c] bf16 (*scale), via LDS transpose
    const float sc = 0.35355339059327373f;
    const float* src = qkv + (size_t)(b * 1536 + 512 + h * 64) * QLD;
    short* dst = kt + ((size_t)head * T_LEN + t0) * D;

    int m = tid & 15, c4 = (tid >> 4) << 2;
    const float* base = src + (size_t)c4 * QLD + t0 + 4 * m;
    const int row = tid >> 3;              // 0..31
    const int off = (tid & 7) * 8;         // shorts

    // all 8 row-loads (tiles A and B) issued before any convert
    f32x4 a0 = *(const f32x4*)base;
    f32x4 a1 = *(const f32x4*)(base + QLD);
    f32x4 a2 = *(const f32x4*)(base + 2 * QLD);
    f32x4 a3 = *(const f32x4*)(base + 3 * QLD);
    f32x4 b0 = *(const f32x4*)(base + 64);
    f32x4 b1 = *(const f32x4*)(base + QLD + 64);
    f32x4 b2 = *(const f32x4*)(base + 2 * QLD + 64);
    f32x4 b3 = *(const f32x4*)(base + 3 * QLD + 64);

    {   // tile A: transpose via LDS (cvt_pk pairs along c)
        #pragma unroll
        for (int j = 0; j < 4; ++j) {
            u32x2 w;
            w[0] = pack2bf(a0[j] * sc, a1[j] * sc);
            w[1] = pack2bf(a2[j] * sc, a3[j] * sc);
            *(u32x2*)&tile[(4 * m + j) * LSTR + c4] = w;
        }
    }
    __syncthreads();
    {   // lane-contiguous coalesced rows [t][c] to global (16B/lane)
        *(s16x8*)(dst + (size_t)row * D + off)        = *(const s16x8*)&tile[row * LSTR + off];
        *(s16x8*)(dst + (size_t)(row + 32) * D + off) = *(const s16x8*)&tile[(row + 32) * LSTR + off];
    }
    __syncthreads();   // WAR: tile A fully read before tile B store
    {   // tile B
        #pragma unroll
        for (int j = 0; j < 4; ++j) {
            u32x2 w;
            w[0] = pack2bf(b0[j] * sc, b1[j] * sc);
            w[1] = pack2bf(b2[j] * sc, b3[j] * sc);
            *(u32x2*)&tile[(4 * m + j) * LSTR + c4] = w;
        }
    }
    __syncthreads();
    {
        short* dstB = dst + 64 * D;
        *(s16x8*)(dstB + (size_t)row * D + off)        = *(const s16x8*)&tile[row * LSTR + off];
        *(s16x8*)(dstB + (size_t)(row + 32) * D + off) = *(const s16x8*)&tile[(row + 32) * LSTR + off];
    }
}

// ---------------- pass 2: attention (R17 loop FROZEN; Q direct-gather) ----
__global__ __launch_bounds__(256, 2)
void attn(const float* __restrict__ qkv, const short* __restrict__ ws16,
          float* __restrict__ out)
{
    // Ping-pong tiles. K: 64 s-rows x 64 shorts, chunk slot c holds global
    // 16B-chunk c ^ sK(row), sK(r) = (r&3)|(((r>>3)&1)<<2).
    // V: 64 c-rows x 64 shorts, chunk slot c holds global chunk c ^ (r&7).
    __shared__ __align__(16) short ktile[2][64 * 64];
    __shared__ __align__(16) short vtile[2][64 * 64];
    __shared__ float lbuf[4][64];
    __shared__ float redbuf[2][64][68];    // [qh][tr][c] fp32 merge staging

    const int tid  = threadIdx.x;
    const int w    = tid >> 6;
    const int qh   = w >> 1;               // q-half (64 rows)
    const int sq   = w & 1;                // s-half of each 64-s tile
    const int lane = tid & 63;
    const int l16  = lane & 15;
    const int quad = lane >> 4;

    // XCD swizzle (verified R6/R7): head ≡ bid (mod 8).
    const int bid  = blockIdx.x;
    const int head = (bid & 7) + 8 * ((bid >> 3) & 3);
    const int t0   = (bid >> 5) * BM;
    const int b    = head >> 3, h = head & 7;

    const short* kt = ws16 + (size_t)NH * T_LEN * D + (size_t)head * T_LEN * D;
    const short* vb = ws16 + 2 * (size_t)NH * T_LEN * D + (size_t)head * D * T_LEN;
    float*       op = out  + (size_t)head * 64 * QLD;

    // R26: Q B-frags gathered directly from fp32 qkv (channel-major), scaled
    // by 1/sqrt(sqrt(ch)) * log2(e), RNE-packed — bitwise-identical to the
    // old scratch path. Once per block, before the DMA prologue.
    const float QSC = 0.35355339059327373f * 1.4426950408889634f;
    const float* qsrc = qkv + (size_t)(b * 1536 + h * 64) * QLD;
    s16x8 bq[NQ][2];
    #pragma unroll
    for (int nq = 0; nq < NQ; ++nq) {
        const int t = t0 + qh * 64 + nq * 16 + l16;
        #pragma unroll
        for (int hf = 0; hf < 2; ++hf) {
            const float* qp = qsrc + (size_t)(hf * 32 + quad * 8) * QLD + t;
            u32x4 qq;
            #pragma unroll
            for (int i = 0; i < 4; ++i) {
                const float v0 = qp[(size_t)(2 * i) * QLD]     * QSC;
                const float v1 = qp[(size_t)(2 * i + 1) * QLD] * QSC;
                qq[i] = pack2bf(v0, v1);
            }
            bq[nq][hf] = __builtin_bit_cast(s16x8, qq);
        }
    }

    // ones A-tile for the l-sum MFMA (bf16 1.0 = 0x3F80)
    s16x8 ones;
    #pragma unroll
    for (int i = 0; i < 8; ++i) ones[i] = (short)0x3F80;

    // persistent zero seed for the QK accumulators
    const f32x4 z4 = f32x4{0.f, 0.f, 0.f, 0.f};

    f32x4 o[NQ][4];
    f32x4 lacc[NQ];
    #pragma unroll
    for (int nq = 0; nq < NQ; ++nq) {
        lacc[nq] = z4;
        #pragma unroll
        for (int ct = 0; ct < 4; ++ct) o[nq][ct] = z4;
    }

    // permuted K row: S C-rows (quad*4+r) land at s = g*32 + quad*8 + r + 4*sub
    const int kperm = (l16 >> 2) * 8 + (l16 & 3);
    const int ksw   = (l16 & 3) | (((l16 >> 2) & 1) << 2);   // = sK(kperm+4sub)
    const int srow  = lane >> 3;       // staging: row within 8-row group
    const int schk  = lane & 7;        // staging: chunk slot
    const int g     = sq;              // this wave's 32-s half

    // staging: wave w stages rows w*16..w*16+15 of K and V tiles.
    const int rl0 = w * 16 + srow;
    const int rl1 = rl0 + 8;
    const int sk0 = (srow & 3) | (((w * 2 + 0) & 1) << 2);
    const int sk1 = (srow & 3) | (((w * 2 + 1) & 1) << 2);
    const short* kge0 = kt + (size_t)rl0 * D + ((schk ^ sk0) << 3);
    const short* kge1 = kt + (size_t)rl1 * D + ((schk ^ sk1) << 3);
    const short* vge0 = vb + (size_t)rl0 * T_LEN + ((schk ^ srow) << 3);
    const short* vge1 = vb + (size_t)rl1 * T_LEN + ((schk ^ srow) << 3);

    // ---- prologue: DMA tile 0 into buf 0 ----
    cp16(kge0, &ktile[0][w * 1024]);
    cp16(kge1, &ktile[0][w * 1024 + 512]);
    cp16(vge0, &vtile[0][w * 1024]);
    cp16(vge1, &vtile[0][w * 1024 + 512]);

    // running DMA pointers for tile it+1 (strength-reduced)
    const short* kp0 = kge0 + 64 * D;
    const short* kp1 = kge1 + 64 * D;
    const short* vp0 = vge0 + 64;
    const short* vp1 = vge1 + 64;

    #pragma unroll 2
    for (int it = 0; it < T_LEN / 64; ++it) {
        const int cur = it & 1;
        __syncthreads();   // buf[cur] DMA drained; prior reads of buf[cur^1] done

        // ---- issue DMA for tile it+1 into buf[cur^1] (async all iter) ----
        if (it + 1 < T_LEN / 64) {
            cp16(kp0, &ktile[cur ^ 1][w * 1024]);        kp0 += 64 * D;
            cp16(kp1, &ktile[cur ^ 1][w * 1024 + 512]);  kp1 += 64 * D;
            cp16(vp0, &vtile[cur ^ 1][w * 1024]);        vp0 += 64;
            cp16(vp1, &vtile[cur ^ 1][w * 1024 + 512]);  vp1 += 64;
        }

        // ---- S' = K*Q on this wave's s-half; p = 2^s; pack ----
        u32x4 bp[NQ];
        #pragma unroll
        for (int sub = 0; sub < 2; ++sub) {
            const int R  = g * 32 + kperm + 4 * sub;
            const int c0 = (quad ^ ksw) << 3;
            s16x8 ak0 = *(const s16x8*)&ktile[cur][R * 64 + c0];
            s16x8 ak1 = *(const s16x8*)&ktile[cur][R * 64 + (c0 ^ 32)];
            #pragma unroll
            for (int nq = 0; nq < NQ; ++nq) {
                f32x4 acc;
                acc = __builtin_amdgcn_mfma_f32_16x16x32_bf16(ak0, bq[nq][0], z4, 0, 0, 0);
                acc = __builtin_amdgcn_mfma_f32_16x16x32_bf16(ak1, bq[nq][1], acc, 0, 0, 0);
                bp[nq][sub * 2]     = pack2bf(EXP2(acc[0]), EXP2(acc[1]));
                bp[nq][sub * 2 + 1] = pack2bf(EXP2(acc[2]), EXP2(acc[3]));
            }
        }
        // ---- O^T += V * P^T ; l += 1 * P^T (ones-MFMA row sum) ----
        s16x8 p[NQ];
        #pragma unroll
        for (int nq = 0; nq < NQ; ++nq) p[nq] = __builtin_bit_cast(s16x8, bp[nq]);
        __builtin_amdgcn_s_setprio(1);
        #pragma unroll
        for (int nq = 0; nq < NQ; ++nq)
            lacc[nq] = __builtin_amdgcn_mfma_f32_16x16x32_bf16(ones, p[nq], lacc[nq], 0, 0, 0);
        #pragma unroll
        for (int ct = 0; ct < 4; ++ct) {
            const int r = ct * 16 + l16;
            s16x8 av = *(const s16x8*)&vtile[cur][r * 64 + ((((g * 4 + quad) ^ (l16 & 7))) << 3)];
            #pragma unroll
            for (int nq = 0; nq < NQ; ++nq)
                o[nq][ct] = __builtin_amdgcn_mfma_f32_16x16x32_bf16(av, p[nq], o[nq][ct], 0, 0, 0);
        }
        __builtin_amdgcn_s_setprio(0);
    }

    // ---- epilogue: s-pair reduction (waves 2qh and 2qh+1) ----
    // lacc[nq][0] holds this wave's full s-half row sum for t=nq*16+l16 (all
    // C rows of the ones-MFMA are identical).
    if (quad == 0) {
        #pragma unroll
        for (int nq = 0; nq < NQ; ++nq) lbuf[w][nq * 16 + l16] = lacc[nq][0];
    }
    __syncthreads();   // all tile reads done; lbuf visible

    if (sq == 1) {
        #pragma unroll
        for (int nq = 0; nq < NQ; ++nq)
            #pragma unroll
            for (int ct = 0; ct < 4; ++ct)
                *(f32x4*)&redbuf[qh][nq * 16 + l16][ct * 16 + quad * 4] = o[nq][ct];
    }
    __syncthreads();
    if (sq == 0) {
        #pragma unroll
        for (int nq = 0; nq < NQ; ++nq) {
            const int tr = nq * 16 + l16;
            const float inv = 1.f / (lbuf[qh * 2][tr] + lbuf[qh * 2 + 1][tr]);
            const int tq = t0 + qh * 64 + tr;
            #pragma unroll
            for (int ct = 0; ct < 4; ++ct) {
                f32x4 a = *(const f32x4*)&redbuf[qh][tr][ct * 16 + quad * 4];
                f32x4 v = o[nq][ct] + a;
                #pragma unroll
                for (int r = 0; r < 4; ++r) {
                    const int c = ct * 16 + quad * 4 + r;
                    op[(size_t)c * QLD + tq] = v[r] * inv;
                }
            }
        }
    }
}

extern "C" void kernel_launch(void* const* d_in, const int* in_sizes, int n_in,
                              void* d_out, int out_size, void* d_ws, size_t ws_size,
                              hipStream_t stream) {
    const float* qkv = (const float*)d_in[0];
    float* out = (float*)d_out;
    short* ws16 = (short*)d_ws;          // scratch: K^T + V bf16 (Q leg unused)

    prep<<<dim3(T_LEN / 128, NH, 2), dim3(256), 0, stream>>>(qkv, ws16);
    attn<<<dim3(T_LEN / BM * NH), dim3(256), 0, stream>>>(qkv, ws16, out);
}